// Round 1
// baseline (629.346 us; speedup 1.0000x reference)
//
#include <hip/hip_runtime.h>

#define B_SZ  128
#define CH    64
#define T_LEN 4096
#define HID   32
#define INS   3

// ---------------------------------------------------------------------------
// Kernel 1: hypernetwork MLPs. One block per batch sample.
//   h = W1 @ z + b1 ; LayerNorm(g,beta) ; ReLU ; out = W2 @ h + b2
// Writes weight TRANSPOSED as wT[b][i][o] (i = ch_in, o = ch_out) so kernel 2
// can read per-i rows as contiguous float4s from LDS.
// ---------------------------------------------------------------------------
__global__ __launch_bounds__(256) void hyper_mlp_kernel(
    const float* __restrict__ z,
    const float* __restrict__ w_w1, const float* __restrict__ w_b1,
    const float* __restrict__ w_g,  const float* __restrict__ w_beta,
    const float* __restrict__ w_w2, const float* __restrict__ w_b2,
    const float* __restrict__ b_w1, const float* __restrict__ b_b1,
    const float* __restrict__ b_g,  const float* __restrict__ b_beta,
    const float* __restrict__ b_w2, const float* __restrict__ b_b2,
    float* __restrict__ wT,    // [B][CH][CH]  (i, o)
    float* __restrict__ bias)  // [B][CH]
{
  const int b   = blockIdx.x;
  const int tid = threadIdx.x;

  __shared__ float zs[INS];
  __shared__ float hraw[2][HID];
  __shared__ float hn[2][HID];

  if (tid < INS) zs[tid] = z[b * INS + tid];
  __syncthreads();

  // first linear: 2 MLPs x 32 hidden units
  if (tid < 2 * HID) {
    const int grp = tid >> 5;          // 0 = weight-MLP, 1 = bias-MLP
    const int j   = tid & 31;
    const float* w1 = grp ? b_w1 : w_w1;
    const float* b1 = grp ? b_b1 : w_b1;
    hraw[grp][j] = w1[j*3+0]*zs[0] + w1[j*3+1]*zs[1] + w1[j*3+2]*zs[2] + b1[j];
  }
  __syncthreads();

  // LayerNorm (population var, /32) + ReLU
  if (tid < 2 * HID) {
    const int grp = tid >> 5;
    const int j   = tid & 31;
    float mu = 0.f;
    #pragma unroll
    for (int k = 0; k < HID; ++k) mu += hraw[grp][k];
    mu *= (1.0f / HID);
    float var = 0.f;
    #pragma unroll
    for (int k = 0; k < HID; ++k) { float d = hraw[grp][k] - mu; var += d * d; }
    var *= (1.0f / HID);
    const float r  = rsqrtf(var + 1e-5f);
    const float* g  = grp ? b_g    : w_g;
    const float* be = grp ? b_beta : w_beta;
    const float v = (hraw[grp][j] - mu) * r * g[j] + be[j];
    hn[grp][j] = fmaxf(v, 0.f);
  }
  __syncthreads();

  // weight head: 4096 outputs per sample, written transposed
  for (int m = tid; m < CH * CH; m += 256) {
    const float* row = w_w2 + m * HID;
    float acc = w_b2[m];
    #pragma unroll
    for (int i = 0; i < HID; ++i) acc += hn[0][i] * row[i];
    // m = o*64 + i  ->  wT[b][i][o]
    wT[(size_t)b * CH * CH + (m & 63) * CH + (m >> 6)] = acc;
  }

  // bias head: 64 outputs per sample
  if (tid < CH) {
    const float* row = b_w2 + tid * HID;
    float acc = b_b2[tid];
    #pragma unroll
    for (int i = 0; i < HID; ++i) acc += hn[1][i] * row[i];
    bias[b * CH + tid] = acc;
  }
}

// ---------------------------------------------------------------------------
// Kernel 2: per-batch 64x64 matrix applied to x[b][64][T].
// Grid: (T/512, B). Block 256 threads. Each thread owns 2 t-columns and all
// 64 outputs (128 fp32 accumulators). Per i-step: 1 coalesced float2 x-load,
// 16 ds_read_b128 LDS broadcasts (same addr all lanes -> conflict-free),
// 128 v_fmac_f32. x read exactly once, out written exactly once.
// ---------------------------------------------------------------------------
__global__ __launch_bounds__(256, 3) void conv1x1_kernel(
    const float* __restrict__ x,
    const float* __restrict__ wT,
    const float* __restrict__ bias,
    float* __restrict__ out)
{
  const int b   = blockIdx.y;
  const int tid = threadIdx.x;
  const int t   = blockIdx.x * 512 + tid * 2;

  __shared__ float wts[CH][CH];   // [i][o]
  __shared__ float bs[CH];

  {
    const float4* src = (const float4*)(wT + (size_t)b * CH * CH);
    float4* dst = (float4*)(&wts[0][0]);
    #pragma unroll
    for (int k = 0; k < 4; ++k) dst[tid + k * 256] = src[tid + k * 256];
    if (tid < CH) bs[tid] = bias[b * CH + tid];
  }
  __syncthreads();

  const float* xp = x + (size_t)b * CH * T_LEN + t;

  float accx[CH], accy[CH];
  #pragma unroll
  for (int o = 0; o < CH; ++o) { accx[o] = 0.f; accy[o] = 0.f; }

  #pragma unroll 2
  for (int i = 0; i < CH; ++i) {
    const float2 xv = *(const float2*)(xp + (size_t)i * T_LEN);
    #pragma unroll
    for (int og = 0; og < 16; ++og) {
      const float4 wv = *(const float4*)(&wts[i][og * 4]);
      accx[og*4+0] += wv.x * xv.x;  accy[og*4+0] += wv.x * xv.y;
      accx[og*4+1] += wv.y * xv.x;  accy[og*4+1] += wv.y * xv.y;
      accx[og*4+2] += wv.z * xv.x;  accy[og*4+2] += wv.z * xv.y;
      accx[og*4+3] += wv.w * xv.x;  accy[og*4+3] += wv.w * xv.y;
    }
  }

  float* op = out + (size_t)b * CH * T_LEN + t;
  #pragma unroll
  for (int o = 0; o < CH; ++o) {
    float2 r;
    r.x = accx[o] + bs[o];
    r.y = accy[o] + bs[o];
    *(float2*)(op + (size_t)o * T_LEN) = r;
  }
}

extern "C" void kernel_launch(void* const* d_in, const int* in_sizes, int n_in,
                              void* d_out, int out_size, void* d_ws, size_t ws_size,
                              hipStream_t stream) {
  const float* x      = (const float*)d_in[0];
  const float* z      = (const float*)d_in[1];
  const float* w_w1   = (const float*)d_in[2];
  const float* w_b1   = (const float*)d_in[3];
  const float* w_g    = (const float*)d_in[4];
  const float* w_beta = (const float*)d_in[5];
  const float* w_w2   = (const float*)d_in[6];
  const float* w_b2   = (const float*)d_in[7];
  const float* b_w1   = (const float*)d_in[8];
  const float* b_b1   = (const float*)d_in[9];
  const float* b_g    = (const float*)d_in[10];
  const float* b_beta = (const float*)d_in[11];
  const float* b_w2   = (const float*)d_in[12];
  const float* b_b2   = (const float*)d_in[13];

  float* out  = (float*)d_out;
  float* wT   = (float*)d_ws;                      // 128*64*64 floats = 2 MB
  float* bias = wT + (size_t)B_SZ * CH * CH;       // 128*64 floats

  hyper_mlp_kernel<<<B_SZ, 256, 0, stream>>>(
      z, w_w1, w_b1, w_g, w_beta, w_w2, w_b2,
      b_w1, b_b1, b_g, b_beta, b_w2, b_b2, wT, bias);

  dim3 grid(T_LEN / 512, B_SZ);
  conv1x1_kernel<<<grid, 256, 0, stream>>>(x, wT, bias, out);
}

// Round 2
// 89.319 us; speedup vs baseline: 7.0461x; 7.0461x over previous
//
#include <hip/hip_runtime.h>

#define B_SZ  128
#define CH    64
#define T_LEN 4096
#define HID   32
#define INS   3
#define TB    256   // t-columns per block

// ---------------------------------------------------------------------------
// Kernel 1: hypernetwork MLPs. One block per batch sample.
// Writes weight TRANSPOSED as wT[b][i][o] so kernel 2 reads per-i rows of
// 4 consecutive outputs as a single float4.
// ---------------------------------------------------------------------------
__global__ __launch_bounds__(256) void hyper_mlp_kernel(
    const float* __restrict__ z,
    const float* __restrict__ w_w1, const float* __restrict__ w_b1,
    const float* __restrict__ w_g,  const float* __restrict__ w_beta,
    const float* __restrict__ w_w2, const float* __restrict__ w_b2,
    const float* __restrict__ b_w1, const float* __restrict__ b_b1,
    const float* __restrict__ b_g,  const float* __restrict__ b_beta,
    const float* __restrict__ b_w2, const float* __restrict__ b_b2,
    float* __restrict__ wT,    // [B][CH_in][CH_out]
    float* __restrict__ bias)  // [B][CH]
{
  const int b   = blockIdx.x;
  const int tid = threadIdx.x;

  __shared__ float zs[INS];
  __shared__ float hraw[2][HID];
  __shared__ float hn[2][HID];

  if (tid < INS) zs[tid] = z[b * INS + tid];
  __syncthreads();

  if (tid < 2 * HID) {
    const int grp = tid >> 5;          // 0 = weight-MLP, 1 = bias-MLP
    const int j   = tid & 31;
    const float* w1 = grp ? b_w1 : w_w1;
    const float* b1 = grp ? b_b1 : w_b1;
    hraw[grp][j] = w1[j*3+0]*zs[0] + w1[j*3+1]*zs[1] + w1[j*3+2]*zs[2] + b1[j];
  }
  __syncthreads();

  if (tid < 2 * HID) {
    const int grp = tid >> 5;
    const int j   = tid & 31;
    float mu = 0.f;
    #pragma unroll
    for (int k = 0; k < HID; ++k) mu += hraw[grp][k];
    mu *= (1.0f / HID);
    float var = 0.f;
    #pragma unroll
    for (int k = 0; k < HID; ++k) { float d = hraw[grp][k] - mu; var += d * d; }
    var *= (1.0f / HID);
    const float r  = rsqrtf(var + 1e-5f);
    const float* g  = grp ? b_g    : w_g;
    const float* be = grp ? b_beta : w_beta;
    const float v = (hraw[grp][j] - mu) * r * g[j] + be[j];
    hn[grp][j] = fmaxf(v, 0.f);
  }
  __syncthreads();

  for (int m = tid; m < CH * CH; m += 256) {
    const float* row = w_w2 + m * HID;
    float acc = w_b2[m];
    #pragma unroll
    for (int i = 0; i < HID; ++i) acc += hn[0][i] * row[i];
    // m = o*64 + i  ->  wT[b][i][o]
    wT[(size_t)b * CH * CH + (m & 63) * CH + (m >> 6)] = acc;
  }

  if (tid < CH) {
    const float* row = b_w2 + tid * HID;
    float acc = b_b2[tid];
    #pragma unroll
    for (int i = 0; i < HID; ++i) acc += hn[1][i] * row[i];
    bias[b * CH + tid] = acc;
  }
}

// ---------------------------------------------------------------------------
// Kernel 2: per-batch 64x64 matrix applied to x[b][64][T].
// Block = 1024 threads = 16 waves. Block handles one b and a 256-wide t-tile.
// x tile [64 i][256 t] staged once in LDS (64 KB). Wave w owns output quad
// o = 4w..4w+3 (weight address wave-uniform -> scalar/broadcast load). Lane
// owns 4 consecutive t. Accumulators: 4 named float4 (16 VGPRs, no arrays ->
// no scratch). Per i-step: 1 ds_read_b128 (wave reads 1KB contiguous,
// bank-perfect) + 1 uniform 16B weight load + 16 v_fmac.
// ---------------------------------------------------------------------------
__global__ __launch_bounds__(1024, 8) void conv1x1_kernel(
    const float* __restrict__ x,
    const float* __restrict__ wT,
    const float* __restrict__ bias,
    float* __restrict__ out)
{
  const int b   = blockIdx.y;
  const int tbi = blockIdx.x;
  const int tid = threadIdx.x;

  __shared__ float4 xs[CH * (TB / 4)];   // [i][c], c = float4 column; 64 KB

  // ---- stage x tile: 4096 float4s, 1024 threads x 4 ----
  const float* xbase = x + (size_t)b * CH * T_LEN + tbi * TB;
  #pragma unroll
  for (int k = 0; k < 4; ++k) {
    const int f = tid + k * 1024;
    const int i = f >> 6;          // row
    const int c = f & 63;          // float4 col
    xs[f] = *(const float4*)(xbase + (size_t)i * T_LEN + c * 4);
  }
  __syncthreads();

  const int lane = tid & 63;
  const int oq   = __builtin_amdgcn_readfirstlane(tid >> 6);  // wave's o-quad, uniform

  const float4* wp = (const float4*)wT + (size_t)b * (CH * CH / 4) + oq;

  float4 a0 = {0.f, 0.f, 0.f, 0.f};
  float4 a1 = {0.f, 0.f, 0.f, 0.f};
  float4 a2 = {0.f, 0.f, 0.f, 0.f};
  float4 a3 = {0.f, 0.f, 0.f, 0.f};

  #pragma unroll
  for (int i = 0; i < CH; ++i) {
    const float4 xv = xs[i * 64 + lane];
    const float4 wv = wp[i * 16];          // wT[b][i][4oq..4oq+3], wave-uniform
    a0.x += wv.x * xv.x; a0.y += wv.x * xv.y; a0.z += wv.x * xv.z; a0.w += wv.x * xv.w;
    a1.x += wv.y * xv.x; a1.y += wv.y * xv.y; a1.z += wv.y * xv.z; a1.w += wv.y * xv.w;
    a2.x += wv.z * xv.x; a2.y += wv.z * xv.y; a2.z += wv.z * xv.z; a2.w += wv.z * xv.w;
    a3.x += wv.w * xv.x; a3.y += wv.w * xv.y; a3.z += wv.w * xv.z; a3.w += wv.w * xv.w;
  }

  const float4 bv = *(const float4*)(bias + b * CH + oq * 4);
  float* op = out + ((size_t)b * CH + oq * 4) * T_LEN + tbi * TB + lane * 4;

  float4 r0 = {a0.x + bv.x, a0.y + bv.x, a0.z + bv.x, a0.w + bv.x};
  float4 r1 = {a1.x + bv.y, a1.y + bv.y, a1.z + bv.y, a1.w + bv.y};
  float4 r2 = {a2.x + bv.z, a2.y + bv.z, a2.z + bv.z, a2.w + bv.z};
  float4 r3 = {a3.x + bv.w, a3.y + bv.w, a3.z + bv.w, a3.w + bv.w};
  *(float4*)(op + 0 * (size_t)T_LEN) = r0;
  *(float4*)(op + 1 * (size_t)T_LEN) = r1;
  *(float4*)(op + 2 * (size_t)T_LEN) = r2;
  *(float4*)(op + 3 * (size_t)T_LEN) = r3;
}

extern "C" void kernel_launch(void* const* d_in, const int* in_sizes, int n_in,
                              void* d_out, int out_size, void* d_ws, size_t ws_size,
                              hipStream_t stream) {
  const float* x      = (const float*)d_in[0];
  const float* z      = (const float*)d_in[1];
  const float* w_w1   = (const float*)d_in[2];
  const float* w_b1   = (const float*)d_in[3];
  const float* w_g    = (const float*)d_in[4];
  const float* w_beta = (const float*)d_in[5];
  const float* w_w2   = (const float*)d_in[6];
  const float* w_b2   = (const float*)d_in[7];
  const float* b_w1   = (const float*)d_in[8];
  const float* b_b1   = (const float*)d_in[9];
  const float* b_g    = (const float*)d_in[10];
  const float* b_beta = (const float*)d_in[11];
  const float* b_w2   = (const float*)d_in[12];
  const float* b_b2   = (const float*)d_in[13];

  float* out  = (float*)d_out;
  float* wT   = (float*)d_ws;                      // 128*64*64 floats = 2 MB
  float* bias = wT + (size_t)B_SZ * CH * CH;       // 128*64 floats

  hyper_mlp_kernel<<<B_SZ, 256, 0, stream>>>(
      z, w_w1, w_b1, w_g, w_beta, w_w2, w_b2,
      b_w1, b_b1, b_g, b_beta, b_w2, b_b2, wT, bias);

  dim3 grid(T_LEN / TB, B_SZ);
  conv1x1_kernel<<<grid, 1024, 0, stream>>>(x, wT, bias, out);
}